// Round 2
// baseline (1210.429 us; speedup 1.0000x reference)
//
#include <hip/hip_runtime.h>

typedef _Float16 half8 __attribute__((ext_vector_type(8)));
typedef _Float16 half2v __attribute__((ext_vector_type(2)));
typedef float floatx4 __attribute__((ext_vector_type(4)));

__device__ __forceinline__ float fast_rcp(float x) { return __builtin_amdgcn_rcpf(x); }
__device__ __forceinline__ float fast_sigmoid(float x) {
  return fast_rcp(1.f + __expf(-x));
}
__device__ __forceinline__ float fast_tanh(float x) {
  return 1.f - 2.f * fast_rcp(1.f + __expf(2.f * x));
}

// ---------------- prep: fp16 fragment-ordered weights + bias sums ----------------
// B-frag layout for mfma_f32_16x16x32_f16: lane L, reg j holds
// W[n = ntile*16 + (L&15)][k = ktile*32 + (L>>4)*8 + j].
// Buffer: [ktile][ntile(32)][lane(64)][8 f16]. Verified correct rounds 1-8 + fused round.
__global__ void prep_kernel(const float* __restrict__ wih0, const float* __restrict__ whh0,
                            const float* __restrict__ bih0, const float* __restrict__ bhh0,
                            const float* __restrict__ wih1, const float* __restrict__ whh1,
                            const float* __restrict__ bih1, const float* __restrict__ bhh1,
                            _Float16* __restrict__ w0f, _Float16* __restrict__ w1f,
                            float* __restrict__ bias0, float* __restrict__ bias1)
{
  int stride = gridDim.x * blockDim.x;
  int idx0 = blockIdx.x * blockDim.x + threadIdx.x;
  const int N0 = 6*32*64*8;      // layer0: K=192 (x 64 | h 128)
  const int N1 = 8*32*64*8;      // layer1: K=256 (h1 128 | h 128)
  for (int e = idx0; e < N0 + N1 + 1024; e += stride) {
    if (e < N0) {
      int j = e & 7; int le = e >> 3; int lane = le & 63; int frag = le >> 6;
      int kt = frag >> 5, ntile = frag & 31;
      int n = ntile*16 + (lane & 15);
      int kk = kt*32 + ((lane >> 4) << 3) + j;
      float v = (kk < 64) ? wih0[n*64 + kk] : whh0[n*128 + (kk - 64)];
      w0f[e] = (_Float16)v;
    } else if (e < N0 + N1) {
      int e2 = e - N0;
      int j = e2 & 7; int le = e2 >> 3; int lane = le & 63; int frag = le >> 6;
      int kt = frag >> 5, ntile = frag & 31;
      int n = ntile*16 + (lane & 15);
      int kk = kt*32 + ((lane >> 4) << 3) + j;
      float v = (kk < 128) ? wih1[n*128 + kk] : whh1[n*128 + (kk - 128)];
      w1f[e2] = (_Float16)v;
    } else {
      int i = e - (N0 + N1);
      if (i < 512) bias0[i] = bih0[i] + bhh0[i];
      else         bias1[i - 512] = bih1[i - 512] + bhh1[i - 512];
    }
  }
}

// ---------------- fused 2-layer LSTM, WAVE-SPECIALIZED ----------------
// 8 waves/block: waves 0-3 run layer 0, waves 4-7 run layer 1 (lag 16 steps).
// Each SIMD hosts one l0 wave + one l1 wave -> independent chains overlap.
// Phase p (0..527): l0 step t0=p (p<512); l1 step t1=p-16 (p>=16).
// Each wave owns 2 column-tiles: slots {wi, wi+4}, en = slot*16 + (lane&15);
// per step 32 MFMAs (4 kt x 4 g x 2 ct), 8 independent acc chains of depth 4.
// pre0/pre1 columns are wave-private (written and read by the same wave).
// Cross-wave traffic (hist: l0->l1 proj; hA*: epilogue->next step) is ordered by
// the single per-phase barrier. hist inner dim padded 128->132 to spread the
// l1-proj A-frag reads across banks (round-1 had 16-way conflicts).
// Recurrent weights resident in AGPRs (32 frags = 128 AGPR/wave); projection
// weights re-read from global per batch (L1-resident after first touch),
// opaque-pointer asm stops LICM from hoisting them into the carried set.
__global__ __launch_bounds__(512, 2) void lstm_fused(const float* __restrict__ x,
    const _Float16* __restrict__ w0f, const float* __restrict__ bias0,
    const _Float16* __restrict__ w1f, const float* __restrict__ bias1,
    const float* __restrict__ wlin, const float* __restrict__ blin,
    float* __restrict__ out)
{
  const int tid = threadIdx.x;
  const int lane = tid & 63;
  const int w = tid >> 6;
  const int layer = w >> 2;               // 0: waves 0-3, 1: waves 4-7
  const int wi = w & 3;
  const int r0 = blockIdx.x * 2;

  __shared__ float pre0[2][8192];         // 64 KB: l0 pre-activations (8 steps x 2 rows)
  __shared__ float pre1[2][8192];         // 64 KB: l1 pre-activations
  __shared__ half8 aF[2][128];            // x A-frags, 2 ktiles (K=64), 4 KB
  __shared__ half8 hA0[2][32];            // compact recurrent frags l0 (1 KB)
  __shared__ half8 hA1[2][32];            // compact recurrent frags l1 (1 KB)
  __shared__ _Float16 hist[16][2][132];   // h0 ring -> l1 proj (padded: bank spread)
  __shared__ float head[256];

  if (tid < 256) { ((int*)hA0)[tid] = 0; ((int*)hA1)[tid] = 0; }

  const _Float16* wf = layer ? w1f : w0f;
  const float* biasp = layer ? bias1 : bias0;
  const int ktoff = layer ? 4 : 2;        // recurrent ktile offset
  const int nktp = layer ? 4 : 2;         // projection ktiles

  // resident recurrent weights: 4 kt x 4 g x 2 ct = 32 frags = 128 AGPRs
  half8 bfr[4][4][2];
#pragma unroll
  for (int kt = 0; kt < 4; ++kt)
#pragma unroll
    for (int g = 0; g < 4; ++g)
#pragma unroll
      for (int ct = 0; ct < 2; ++ct) {
        int frag = (kt + ktoff)*32 + g*8 + wi + 4*ct;
        bfr[kt][g][ct] = *reinterpret_cast<const half8*>(wf + (size_t)(frag*64 + lane)*8);
        asm volatile("" : "+a"(bfr[kt][g][ct]));
      }

  const int li = lane & 15;
  float b_v[4][2];
#pragma unroll
  for (int g = 0; g < 4; ++g) {
    b_v[g][0] = biasp[g*128 + wi*16 + li];
    b_v[g][1] = biasp[g*128 + (wi+4)*16 + li];
  }

  // x staging: thread -> (dt, r, col-pair); full A-frag half index
  const int sdt = tid >> 6, sr = (tid >> 5) & 1, scp = (tid & 31) * 2;
  const int sm = sdt*2 + sr;
  const int sidx = ((scp>>5)*64 + sm + (((scp&31)>>3)<<4))*8 + (scp & 7);

  const bool arow = (lane & 11) == 0;
  const int cIdx = ((lane >> 4) << 1) | ((lane >> 2) & 1);
  const int rb = lane >> 4;
  const int en0 = wi*16 + li;
  const int en1 = en0 + 64;
  const int eoff0 = ((en0>>5)*8 + ((en0&31)>>3)*2 + rb)*8 + (en0&7);
  const int eoff1 = ((en1>>5)*8 + ((en1&31)>>3)*2 + rb)*8 + (en1&7);
  float wl0 = 0.f, wl1 = 0.f;
  if (layer && lane < 32) { wl0 = wlin[en0]; wl1 = wlin[en1]; }
  float cst_0 = 0.f, cst_1 = 0.f, hl0 = 0.f, hl1 = 0.f;

  // l1-proj A addressing into hist: lane L holds A[m=L&15][k=(L>>4)*8+j+kt*32],
  // m = dt*2 + r  ->  step = 8*bb + dt, row = r.
  const int dtL = (lane & 15) >> 1;
  const int rL  = lane & 1;
  const int kbase = (lane >> 4) * 8;

  half8 (*hAc)[32] = layer ? hA1 : hA0;
  float (*prep_)[8192] = layer ? pre1 : pre0;

  // prologue: stage x batches 0 and 1 (all waves)
  {
    float2 v0 = *reinterpret_cast<const float2*>(x + ((size_t)(r0+sr)*512 + sdt)*64 + scp);
    float2 v1 = *reinterpret_cast<const float2*>(x + ((size_t)(r0+sr)*512 + 8 + sdt)*64 + scp);
    half2v h0; h0[0] = (_Float16)v0.x; h0[1] = (_Float16)v0.y;
    half2v h1v; h1v[0] = (_Float16)v1.x; h1v[1] = (_Float16)v1.y;
    *reinterpret_cast<half2v*>(((_Float16*)aF[0]) + sidx) = h0;
    *reinterpret_cast<half2v*>(((_Float16*)aF[1]) + sidx) = h1v;
  }
  __syncthreads();
  if (layer == 0) {                        // l0 pre[batch0] -> pre0[0]
    floatx4 accP[4][2];
#pragma unroll
    for (int g = 0; g < 4; ++g)
#pragma unroll
      for (int ct = 0; ct < 2; ++ct) {
        float bb = b_v[g][ct]; accP[g][ct] = (floatx4){bb,bb,bb,bb};
      }
#pragma unroll
    for (int kt = 0; kt < 2; ++kt) {
      half8 af = aF[0][kt*64 + lane];
#pragma unroll
      for (int g = 0; g < 4; ++g)
#pragma unroll
        for (int ct = 0; ct < 2; ++ct) {
          half8 wfr = *reinterpret_cast<const half8*>(wf + (size_t)(((kt*32 + g*8 + wi + 4*ct))*64 + lane)*8);
          accP[g][ct] = __builtin_amdgcn_mfma_f32_16x16x32_f16(af, wfr, accP[g][ct], 0, 0, 0);
        }
    }
#pragma unroll
    for (int reg = 0; reg < 4; ++reg) {
      int m = ((lane>>4)<<2) + reg;
      floatx4 pv0 = (floatx4){accP[0][0][reg], accP[1][0][reg], accP[2][0][reg], accP[3][0][reg]};
      floatx4 pv1 = (floatx4){accP[0][1][reg], accP[1][1][reg], accP[2][1][reg], accP[3][1][reg]};
      *reinterpret_cast<floatx4*>(&pre0[0][(m*128 + en0)*4]) = pv0;
      *reinterpret_cast<floatx4*>(&pre0[0][(m*128 + en1)*4]) = pv1;
    }
  }
  __syncthreads();

  half8 a0 = {}, a1 = {}, a2 = {}, a3 = {};

  for (int p = 0; p < 528; ++p) {
    const int b = p >> 3;
    if ((p & 7) == 0 && b < 62) {          // stage x batch b+2 -> aF[b&1] (all waves)
      int s = (b+2)*8 + sdt;
      float2 v = *reinterpret_cast<const float2*>(x + ((size_t)(r0+sr)*512 + s)*64 + scp);
      half2v hv; hv[0] = (_Float16)v.x; hv[1] = (_Float16)v.y;
      *reinterpret_cast<half2v*>(((_Float16*)aF[b&1]) + sidx) = hv;
    }
    __syncthreads();

    if ((p & 7) == 0) {
      const _Float16* wp = wf; asm volatile("" : "+v"(wp));
      int bb = layer ? (b - 1) : (b + 1);  // which batch to project
      bool doproj = layer ? (bb >= 0 && bb < 64) : (bb < 63 + 1 && b < 63);
      if (doproj) {
        int slot = bb & 1;
        floatx4 accP[4][2];
#pragma unroll
        for (int g = 0; g < 4; ++g)
#pragma unroll
          for (int ct = 0; ct < 2; ++ct) {
            float bv = b_v[g][ct]; accP[g][ct] = (floatx4){bv,bv,bv,bv};
          }
        if (layer == 0) {
#pragma unroll
          for (int kt = 0; kt < 2; ++kt) {
            half8 af = aF[slot][kt*64 + lane];
#pragma unroll
            for (int g = 0; g < 4; ++g)
#pragma unroll
              for (int ct = 0; ct < 2; ++ct) {
                half8 wfr = *reinterpret_cast<const half8*>(wp + (size_t)((kt*32 + g*8 + wi + 4*ct)*64 + lane)*8);
                accP[g][ct] = __builtin_amdgcn_mfma_f32_16x16x32_f16(af, wfr, accP[g][ct], 0, 0, 0);
              }
          }
        } else {
          const _Float16* hrow = &hist[(bb & 1)*8 + dtL][rL][kbase];
#pragma unroll
          for (int kt = 0; kt < 4; ++kt) {
            half8 af = *reinterpret_cast<const half8*>(hrow + kt*32);
#pragma unroll
            for (int g = 0; g < 4; ++g)
#pragma unroll
              for (int ct = 0; ct < 2; ++ct) {
                half8 wfr = *reinterpret_cast<const half8*>(wp + (size_t)((kt*32 + g*8 + wi + 4*ct)*64 + lane)*8);
                accP[g][ct] = __builtin_amdgcn_mfma_f32_16x16x32_f16(af, wfr, accP[g][ct], 0, 0, 0);
              }
          }
        }
        float* preb = prep_[slot];
#pragma unroll
        for (int reg = 0; reg < 4; ++reg) {
          int m = ((lane>>4)<<2) + reg;
          floatx4 pv0 = (floatx4){accP[0][0][reg], accP[1][0][reg], accP[2][0][reg], accP[3][0][reg]};
          floatx4 pv1 = (floatx4){accP[0][1][reg], accP[1][1][reg], accP[2][1][reg], accP[3][1][reg]};
          *reinterpret_cast<floatx4*>(&preb[(m*128 + en0)*4]) = pv0;
          *reinterpret_cast<floatx4*>(&preb[(m*128 + en1)*4]) = pv1;
        }
      }
    }

    // ---------------- this wave's layer step ----------------
    const int t = layer ? (p - 16) : p;
    if (t >= 0 && t < 512) {
      const int bt = t >> 3;
      const float* preb = prep_[bt & 1];
      floatx4 p40 = (floatx4){0.f,0.f,0.f,0.f}, p41 = (floatx4){0.f,0.f,0.f,0.f};
      if (lane < 32) {
        int mstep = ((t & 7) << 1) + rb;
        p40 = *reinterpret_cast<const floatx4*>(&preb[(mstep*128 + en0)*4]);
        p41 = *reinterpret_cast<const floatx4*>(&preb[(mstep*128 + en1)*4]);
      }
      floatx4 acc[4][2];
#pragma unroll
      for (int g = 0; g < 4; ++g) {
        acc[g][0] = (floatx4){p40[g], 0.f, 0.f, 0.f};
        acc[g][1] = (floatx4){p41[g], 0.f, 0.f, 0.f};
      }

      const int cur = t & 1;
      if (arow) {
        a0 = hAc[cur][0*8 + cIdx];
        a1 = hAc[cur][1*8 + cIdx];
        a2 = hAc[cur][2*8 + cIdx];
        a3 = hAc[cur][3*8 + cIdx];
      }
#pragma unroll
      for (int g = 0; g < 4; ++g) {
        acc[g][0] = __builtin_amdgcn_mfma_f32_16x16x32_f16(a0, bfr[0][g][0], acc[g][0], 0, 0, 0);
        acc[g][1] = __builtin_amdgcn_mfma_f32_16x16x32_f16(a0, bfr[0][g][1], acc[g][1], 0, 0, 0);
      }
#pragma unroll
      for (int g = 0; g < 4; ++g) {
        acc[g][0] = __builtin_amdgcn_mfma_f32_16x16x32_f16(a1, bfr[1][g][0], acc[g][0], 0, 0, 0);
        acc[g][1] = __builtin_amdgcn_mfma_f32_16x16x32_f16(a1, bfr[1][g][1], acc[g][1], 0, 0, 0);
      }
#pragma unroll
      for (int g = 0; g < 4; ++g) {
        acc[g][0] = __builtin_amdgcn_mfma_f32_16x16x32_f16(a2, bfr[2][g][0], acc[g][0], 0, 0, 0);
        acc[g][1] = __builtin_amdgcn_mfma_f32_16x16x32_f16(a2, bfr[2][g][1], acc[g][1], 0, 0, 0);
      }
#pragma unroll
      for (int g = 0; g < 4; ++g) {
        acc[g][0] = __builtin_amdgcn_mfma_f32_16x16x32_f16(a3, bfr[3][g][0], acc[g][0], 0, 0, 0);
        acc[g][1] = __builtin_amdgcn_mfma_f32_16x16x32_f16(a3, bfr[3][g][1], acc[g][1], 0, 0, 0);
      }

      if (lane < 32) {
        float i0 = fast_sigmoid(acc[0][0][0]);
        float f0 = fast_sigmoid(acc[1][0][0]);
        float g0 = fast_tanh(acc[2][0][0]);
        float o0 = fast_sigmoid(acc[3][0][0]);
        float i1 = fast_sigmoid(acc[0][1][0]);
        float f1 = fast_sigmoid(acc[1][1][0]);
        float g1 = fast_tanh(acc[2][1][0]);
        float o1 = fast_sigmoid(acc[3][1][0]);
        cst_0 = f0*cst_0 + i0*g0;
        cst_1 = f1*cst_1 + i1*g1;
        float h0v = o0*fast_tanh(cst_0);
        float h1v = o1*fast_tanh(cst_1);
        _Float16 hh0 = (_Float16)h0v;
        _Float16 hh1 = (_Float16)h1v;
        ((_Float16*)hAc[cur^1])[eoff0] = hh0;
        ((_Float16*)hAc[cur^1])[eoff1] = hh1;
        if (layer == 0) {
          hist[t & 15][rb][en0] = hh0;
          hist[t & 15][rb][en1] = hh1;
        } else {
          hl0 = h0v; hl1 = h1v;
        }
      }
    }
  }

  // fused head: out[r] = sum_n h_last[r][n]*wlin[n] + blin
  if (layer && lane < 32) {
    head[rb*128 + en0] = hl0 * wl0;
    head[rb*128 + en1] = hl1 * wl1;
  }
  __syncthreads();
  if (tid < 2) {
    float s = blin[0];
    for (int n = 0; n < 128; ++n) s += head[tid*128 + n];
    out[r0 + tid] = s;
  }
}

extern "C" void kernel_launch(void* const* d_in, const int* in_sizes, int n_in,
                              void* d_out, int out_size, void* d_ws, size_t ws_size,
                              hipStream_t stream)
{
  const float* x    = (const float*)d_in[0];
  const float* wih0 = (const float*)d_in[1];
  const float* whh0 = (const float*)d_in[2];
  const float* bih0 = (const float*)d_in[3];
  const float* bhh0 = (const float*)d_in[4];
  const float* wih1 = (const float*)d_in[5];
  const float* whh1 = (const float*)d_in[6];
  const float* bih1 = (const float*)d_in[7];
  const float* bhh1 = (const float*)d_in[8];
  const float* wlin = (const float*)d_in[9];
  const float* blin = (const float*)d_in[10];
  float* out = (float*)d_out;

  char* ws = (char*)d_ws;
  _Float16* w0f = (_Float16*)(ws);               // 196608 B
  _Float16* w1f = (_Float16*)(ws + 196608);      // 262144 B
  float* bias0  = (float*)(ws + 458752);         // 2048 B
  float* bias1  = (float*)(ws + 460800);         // 2048 B

  prep_kernel<<<256, 256, 0, stream>>>(wih0, whh0, bih0, bhh0, wih1, whh1, bih1, bhh1,
                                       w0f, w1f, bias0, bias1);
  lstm_fused<<<256, 512, 0, stream>>>(x, w0f, bias0, w1f, bias1, wlin, blin, out);
}

// Round 3
// 724.824 us; speedup vs baseline: 1.6700x; 1.6700x over previous
//
#include <hip/hip_runtime.h>

typedef _Float16 half8 __attribute__((ext_vector_type(8)));
typedef _Float16 half4 __attribute__((ext_vector_type(4)));
typedef _Float16 half2v __attribute__((ext_vector_type(2)));
typedef float floatx4 __attribute__((ext_vector_type(4)));

__device__ __forceinline__ float fast_rcp(float x) { return __builtin_amdgcn_rcpf(x); }
__device__ __forceinline__ float fast_sigmoid(float x) {
  return fast_rcp(1.f + __expf(-x));
}
__device__ __forceinline__ float fast_tanh(float x) {
  return 1.f - 2.f * fast_rcp(1.f + __expf(2.f * x));
}

// ---------------- prep: fp16 fragment-ordered weights + bias sums ----------------
// B-frag layout for mfma_f32_16x16x32_f16: lane L, reg j holds
// W[n = ntile*16 + (L&15)][k = ktile*32 + (L>>4)*8 + j].
// Buffer: [ktile][ntile(32)][lane(64)][8 f16]. Verified correct rounds 1-8.
__global__ void prep_kernel(const float* __restrict__ wih0, const float* __restrict__ whh0,
                            const float* __restrict__ bih0, const float* __restrict__ bhh0,
                            const float* __restrict__ wih1, const float* __restrict__ whh1,
                            const float* __restrict__ bih1, const float* __restrict__ bhh1,
                            _Float16* __restrict__ w0f, _Float16* __restrict__ w1f,
                            float* __restrict__ bias0, float* __restrict__ bias1)
{
  int stride = gridDim.x * blockDim.x;
  int idx0 = blockIdx.x * blockDim.x + threadIdx.x;
  const int N0 = 6*32*64*8;      // layer0: K=192 (x 64 | h 128)
  const int N1 = 8*32*64*8;      // layer1: K=256 (h1 128 | h 128)
  for (int e = idx0; e < N0 + N1 + 1024; e += stride) {
    if (e < N0) {
      int j = e & 7; int le = e >> 3; int lane = le & 63; int frag = le >> 6;
      int kt = frag >> 5, ntile = frag & 31;
      int n = ntile*16 + (lane & 15);
      int kk = kt*32 + ((lane >> 4) << 3) + j;
      float v = (kk < 64) ? wih0[n*64 + kk] : whh0[n*128 + (kk - 64)];
      w0f[e] = (_Float16)v;
    } else if (e < N0 + N1) {
      int e2 = e - N0;
      int j = e2 & 7; int le = e2 >> 3; int lane = le & 63; int frag = le >> 6;
      int kt = frag >> 5, ntile = frag & 31;
      int n = ntile*16 + (lane & 15);
      int kk = kt*32 + ((lane >> 4) << 3) + j;
      float v = (kk < 128) ? wih1[n*128 + kk] : whh1[n*128 + (kk - 128)];
      w1f[e2] = (_Float16)v;
    } else {
      int i = e - (N0 + N1);
      if (i < 512) bias0[i] = bih0[i] + bhh0[i];
      else         bias1[i - 512] = bih1[i - 512] + bhh1[i - 512];
    }
  }
}

// ---------------- layer 0 ----------------
// Structure = proven 785us baseline, with two latency cuts:
//  (1) stage split: global load issued at top of phase 8b (post-barrier, ~full
//      phase of slack before the next barrier's vmcnt(0) drain), LDS-write of
//      the stashed value at phase 8b+1. Removes a ~900-cyc HBM drain stall
//      every 8th phase (baseline issued the load right before __syncthreads).
//  (2) pre-activation fold: step MFMAs seed from 0; preLDS value added in the
//      epilogue instead. Takes the ~120-cyc preLDS lgkm wait off the front of
//      the recurrent MFMA chain (it now resolves ~600 cyc later, fully hidden).
__global__ __launch_bounds__(512, 2) void lstm_l0(const float* __restrict__ x,
    const _Float16* __restrict__ w0f, const float* __restrict__ bias0,
    _Float16* __restrict__ h1out)
{
  const int tid = threadIdx.x;
  const int lane = tid & 63;
  const int w = tid >> 6;
  const int r0 = blockIdx.x * 2;

  __shared__ float preLDS[2][8192];       // 2 x 32 KB pre-activation buffers
  __shared__ half8 aF[2][2*64];           // input A-frags, 2 ktiles (K=64), 2 x 2 KB
  __shared__ half8 hA[2][4*8];            // compact recurrent frags (1 KB)
  __shared__ _Float16 hist[16][2][128];   // h history ring (8 KB)

  for (int i = tid; i < 2*4*8*4; i += 512) ((int*)hA)[i] = 0;

  half8 bf[6][4];                         // 24 frags = 96 AGPRs
#pragma unroll
  for (int kt = 0; kt < 6; ++kt)
#pragma unroll
    for (int g = 0; g < 4; ++g) {
      int frag = kt*32 + (g*8 + w);
      bf[kt][g] = *reinterpret_cast<const half8*>(w0f + (size_t)(frag*64 + lane)*8);
      asm volatile("" : "+a"(bf[kt][g]));
    }
  float bias_v[4];
#pragma unroll
  for (int g = 0; g < 4; ++g) bias_v[g] = bias0[g*128 + w*16 + (lane & 15)];

  // staging: thread -> (dt, r, col-pair); full A-frag half index
  const int sdt = tid >> 6, sr = (tid >> 5) & 1, scp = (tid & 31) * 2;
  const int sm = sdt*2 + sr;
  const int sidx = ((scp>>5)*64 + sm + (((scp&31)>>3)<<4))*8 + (scp & 7);

  const bool arow = (lane & 11) == 0;
  const int cIdx = ((lane >> 4) << 1) | ((lane >> 2) & 1);
  const int rb = lane >> 4;
  const int en = w*16 + (lane & 15);
  const int eoff = ((en>>5)*8 + ((en&31)>>3)*2 + rb)*8 + (en&7);
  float cst = 0.f;

  // prologue: stage batches 0 and 1
  {
    float2 v0 = *reinterpret_cast<const float2*>(x + ((size_t)(r0+sr)*512 + sdt)*64 + scp);
    float2 v1 = *reinterpret_cast<const float2*>(x + ((size_t)(r0+sr)*512 + 8 + sdt)*64 + scp);
    half2v h0; h0[0] = (_Float16)v0.x; h0[1] = (_Float16)v0.y;
    half2v h1v; h1v[0] = (_Float16)v1.x; h1v[1] = (_Float16)v1.y;
    *reinterpret_cast<half2v*>(((_Float16*)aF[0]) + sidx) = h0;
    *reinterpret_cast<half2v*>(((_Float16*)aF[1]) + sidx) = h1v;
  }
  __syncthreads();
  {                                        // pre[batch0] -> preLDS[0]
    floatx4 accP[4];
#pragma unroll
    for (int g = 0; g < 4; ++g) { float bb = bias_v[g]; accP[g] = (floatx4){bb,bb,bb,bb}; }
#pragma unroll
    for (int kt = 0; kt < 2; ++kt) {
      half8 af = aF[0][kt*64 + lane];
#pragma unroll
      for (int g = 0; g < 4; ++g)
        accP[g] = __builtin_amdgcn_mfma_f32_16x16x32_f16(af, bf[kt][g], accP[g], 0, 0, 0);
    }
#pragma unroll
    for (int reg = 0; reg < 4; ++reg) {
      int m = ((lane>>4)<<2) + reg;
      floatx4 pv = (floatx4){accP[0][reg], accP[1][reg], accP[2][reg], accP[3][reg]};
      *reinterpret_cast<floatx4*>(&preLDS[0][(m*128 + en)*4]) = pv;
    }
  }

  half8 a2 = {}, a3 = {}, a4 = {}, a5 = {};
  float2 sv;                               // stage stash (T14 split)

  for (int t = 0; t < 512; ++t) {
    const int b = t >> 3;
    __syncthreads();
    if ((t & 7) == 0 && b < 62) {          // issue stage load for batch b+2
      int s = (b+2)*8 + sdt;
      sv = *reinterpret_cast<const float2*>(x + ((size_t)(r0+sr)*512 + s)*64 + scp);
    }
    if ((t & 7) == 1 && b < 62) {          // write stashed batch b+2 -> aF[b&1]
      half2v hv; hv[0] = (_Float16)sv.x; hv[1] = (_Float16)sv.y;
      *reinterpret_cast<half2v*>(((_Float16*)aF[b&1]) + sidx) = hv;
    }
    if ((t & 7) == 0) {
      if (t != 0) {                        // coalesced flush of steps t-8..t-1
        int tbase = t - 8;
        int fr = tid >> 8, rest = tid & 255;
        int fdt = rest >> 5, n = (rest & 31) * 4;
        half4 v = *reinterpret_cast<const half4*>(&hist[(tbase + fdt) & 15][fr][n]);
        *reinterpret_cast<half4*>(h1out + ((size_t)(r0 + fr)*512 + tbase + fdt)*128 + n) = v;
      }
      if (b < 63) {                        // pre[batch b+1] -> preLDS[(b+1)&1]
        int slot = (b+1) & 1;
        floatx4 accP[4];
#pragma unroll
        for (int g = 0; g < 4; ++g) { float bb = bias_v[g]; accP[g] = (floatx4){bb,bb,bb,bb}; }
#pragma unroll
        for (int kt = 0; kt < 2; ++kt) {
          half8 af = aF[slot][kt*64 + lane];
#pragma unroll
          for (int g = 0; g < 4; ++g)
            accP[g] = __builtin_amdgcn_mfma_f32_16x16x32_f16(af, bf[kt][g], accP[g], 0, 0, 0);
        }
#pragma unroll
        for (int reg = 0; reg < 4; ++reg) {
          int m = ((lane>>4)<<2) + reg;
          floatx4 pv = (floatx4){accP[0][reg], accP[1][reg], accP[2][reg], accP[3][reg]};
          *reinterpret_cast<floatx4*>(&preLDS[slot][(m*128 + en)*4]) = pv;
        }
      }
    }

    // pre-activation read: needed only in the epilogue (fold), huge slack
    floatx4 p4 = (floatx4){0.f, 0.f, 0.f, 0.f};
    if (lane < 32) {
      int mstep = ((t & 7) << 1) + rb;
      p4 = *reinterpret_cast<const floatx4*>(&preLDS[b & 1][(mstep*128 + en)*4]);
    }
    floatx4 acc[4];
#pragma unroll
    for (int g = 0; g < 4; ++g) acc[g] = (floatx4){0.f, 0.f, 0.f, 0.f};

    const int cur = t & 1;
    if (arow) {
      a2 = hA[cur][0*8 + cIdx];
      a3 = hA[cur][1*8 + cIdx];
      a4 = hA[cur][2*8 + cIdx];
      a5 = hA[cur][3*8 + cIdx];
    }
#pragma unroll
    for (int g = 0; g < 4; ++g)
      acc[g] = __builtin_amdgcn_mfma_f32_16x16x32_f16(a2, bf[2][g], acc[g], 0, 0, 0);
#pragma unroll
    for (int g = 0; g < 4; ++g)
      acc[g] = __builtin_amdgcn_mfma_f32_16x16x32_f16(a3, bf[3][g], acc[g], 0, 0, 0);
#pragma unroll
    for (int g = 0; g < 4; ++g)
      acc[g] = __builtin_amdgcn_mfma_f32_16x16x32_f16(a4, bf[4][g], acc[g], 0, 0, 0);
#pragma unroll
    for (int g = 0; g < 4; ++g)
      acc[g] = __builtin_amdgcn_mfma_f32_16x16x32_f16(a5, bf[5][g], acc[g], 0, 0, 0);

    if (lane < 32) {
      float ii = fast_sigmoid(p4[0] + acc[0][0]);
      float ff = fast_sigmoid(p4[1] + acc[1][0]);
      float gg = fast_tanh(p4[2] + acc[2][0]);
      float oo = fast_sigmoid(p4[3] + acc[3][0]);
      cst = ff*cst + ii*gg;
      float hv2 = oo*fast_tanh(cst);
      _Float16 hh = (_Float16)hv2;
      ((_Float16*)hA[cur^1])[eoff] = hh;
      hist[t & 15][rb][en] = hh;
    }
  }
  __syncthreads();
  {                                        // final flush: steps 504..511
    int tbase = 504;
    int fr = tid >> 8, rest = tid & 255;
    int fdt = rest >> 5, n = (rest & 31) * 4;
    half4 v = *reinterpret_cast<const half4*>(&hist[(tbase + fdt) & 15][fr][n]);
    *reinterpret_cast<half4*>(h1out + ((size_t)(r0 + fr)*512 + tbase + fdt)*128 + n) = v;
  }
}

// ---------------- layer 1: K_in = 128 (4 ktiles), fused linear head ----------------
// Same two latency cuts as layer 0.
__global__ __launch_bounds__(512, 2) void lstm_l1(const _Float16* __restrict__ h1in,
    const _Float16* __restrict__ w1f, const float* __restrict__ bias1,
    const float* __restrict__ wlin, const float* __restrict__ blin,
    float* __restrict__ out)
{
  const int tid = threadIdx.x;
  const int lane = tid & 63;
  const int w = tid >> 6;
  const int r0 = blockIdx.x * 2;

  __shared__ float preLDS[2][8192];       // 2 x 32 KB
  __shared__ half8 aF[2][4*64];           // input A-frags, 4 ktiles (K=128), 2 x 4 KB
  __shared__ half8 hA[2][4*8];
  __shared__ float head[256];

  for (int i = tid; i < 2*4*8*4; i += 512) ((int*)hA)[i] = 0;

  half8 bf[8][4];                         // 32 frags = 128 AGPRs
#pragma unroll
  for (int kt = 0; kt < 8; ++kt)
#pragma unroll
    for (int g = 0; g < 4; ++g) {
      int frag = kt*32 + (g*8 + w);
      bf[kt][g] = *reinterpret_cast<const half8*>(w1f + (size_t)(frag*64 + lane)*8);
      asm volatile("" : "+a"(bf[kt][g]));
    }
  float bias_v[4];
#pragma unroll
  for (int g = 0; g < 4; ++g) bias_v[g] = bias1[g*128 + w*16 + (lane & 15)];

  // staging: thread -> (dt, r, col-quad); fp16 passthrough (8B)
  const int sdt = tid >> 6, sr = (tid >> 5) & 1, scq = (tid & 31) * 4;
  const int sm = sdt*2 + sr;
  const int sidx = ((scq>>5)*64 + sm + (((scq&31)>>3)<<4))*8 + (scq & 7);

  const bool arow = (lane & 11) == 0;
  const int cIdx = ((lane >> 4) << 1) | ((lane >> 2) & 1);
  const int rb = lane >> 4;
  const int en = w*16 + (lane & 15);
  const int eoff = ((en>>5)*8 + ((en&31)>>3)*2 + rb)*8 + (en&7);
  const float wl = (lane < 32) ? wlin[en] : 0.f;
  float cst = 0.f;
  float hl = 0.f;

  // prologue: stage batches 0 and 1
  {
    uint2 v0 = *reinterpret_cast<const uint2*>(h1in + ((size_t)(r0+sr)*512 + sdt)*128 + scq);
    uint2 v1 = *reinterpret_cast<const uint2*>(h1in + ((size_t)(r0+sr)*512 + 8 + sdt)*128 + scq);
    *reinterpret_cast<uint2*>(((_Float16*)aF[0]) + sidx) = v0;
    *reinterpret_cast<uint2*>(((_Float16*)aF[1]) + sidx) = v1;
  }
  __syncthreads();
  {                                        // pre[batch0] -> preLDS[0]
    floatx4 accP[4];
#pragma unroll
    for (int g = 0; g < 4; ++g) { float bb = bias_v[g]; accP[g] = (floatx4){bb,bb,bb,bb}; }
#pragma unroll
    for (int kt = 0; kt < 4; ++kt) {
      half8 af = aF[0][kt*64 + lane];
#pragma unroll
      for (int g = 0; g < 4; ++g)
        accP[g] = __builtin_amdgcn_mfma_f32_16x16x32_f16(af, bf[kt][g], accP[g], 0, 0, 0);
    }
#pragma unroll
    for (int reg = 0; reg < 4; ++reg) {
      int m = ((lane>>4)<<2) + reg;
      floatx4 pv = (floatx4){accP[0][reg], accP[1][reg], accP[2][reg], accP[3][reg]};
      *reinterpret_cast<floatx4*>(&preLDS[0][(m*128 + en)*4]) = pv;
    }
  }

  half8 a4 = {}, a5 = {}, a6 = {}, a7 = {};
  uint2 sv;                                // stage stash (T14 split)

  for (int t = 0; t < 512; ++t) {
    const int b = t >> 3;
    __syncthreads();
    if ((t & 7) == 0 && b < 62) {          // issue stage load for batch b+2
      int s = (b+2)*8 + sdt;
      sv = *reinterpret_cast<const uint2*>(h1in + ((size_t)(r0+sr)*512 + s)*128 + scq);
    }
    if ((t & 7) == 1 && b < 62) {          // write stashed batch b+2 -> aF[b&1]
      *reinterpret_cast<uint2*>(((_Float16*)aF[b&1]) + sidx) = sv;
    }
    if ((t & 7) == 0 && b < 63) {          // pre[batch b+1] -> preLDS[(b+1)&1]
      int slot = (b+1) & 1;
      floatx4 accP[4];
#pragma unroll
      for (int g = 0; g < 4; ++g) { float bb = bias_v[g]; accP[g] = (floatx4){bb,bb,bb,bb}; }
#pragma unroll
      for (int kt = 0; kt < 4; ++kt) {
        half8 af = aF[slot][kt*64 + lane];
#pragma unroll
        for (int g = 0; g < 4; ++g)
          accP[g] = __builtin_amdgcn_mfma_f32_16x16x32_f16(af, bf[kt][g], accP[g], 0, 0, 0);
      }
#pragma unroll
      for (int reg = 0; reg < 4; ++reg) {
        int m = ((lane>>4)<<2) + reg;
        floatx4 pv = (floatx4){accP[0][reg], accP[1][reg], accP[2][reg], accP[3][reg]};
        *reinterpret_cast<floatx4*>(&preLDS[slot][(m*128 + en)*4]) = pv;
      }
    }

    // pre-activation read: needed only in the epilogue (fold), huge slack
    floatx4 p4 = (floatx4){0.f, 0.f, 0.f, 0.f};
    if (lane < 32) {
      int mstep = ((t & 7) << 1) + rb;
      p4 = *reinterpret_cast<const floatx4*>(&preLDS[b & 1][(mstep*128 + en)*4]);
    }
    floatx4 acc[4];
#pragma unroll
    for (int g = 0; g < 4; ++g) acc[g] = (floatx4){0.f, 0.f, 0.f, 0.f};

    const int cur = t & 1;
    if (arow) {
      a4 = hA[cur][0*8 + cIdx];
      a5 = hA[cur][1*8 + cIdx];
      a6 = hA[cur][2*8 + cIdx];
      a7 = hA[cur][3*8 + cIdx];
    }
#pragma unroll
    for (int g = 0; g < 4; ++g)
      acc[g] = __builtin_amdgcn_mfma_f32_16x16x32_f16(a4, bf[4][g], acc[g], 0, 0, 0);
#pragma unroll
    for (int g = 0; g < 4; ++g)
      acc[g] = __builtin_amdgcn_mfma_f32_16x16x32_f16(a5, bf[5][g], acc[g], 0, 0, 0);
#pragma unroll
    for (int g = 0; g < 4; ++g)
      acc[g] = __builtin_amdgcn_mfma_f32_16x16x32_f16(a6, bf[6][g], acc[g], 0, 0, 0);
#pragma unroll
    for (int g = 0; g < 4; ++g)
      acc[g] = __builtin_amdgcn_mfma_f32_16x16x32_f16(a7, bf[7][g], acc[g], 0, 0, 0);

    if (lane < 32) {
      float ii = fast_sigmoid(p4[0] + acc[0][0]);
      float ff = fast_sigmoid(p4[1] + acc[1][0]);
      float gg = fast_tanh(p4[2] + acc[2][0]);
      float oo = fast_sigmoid(p4[3] + acc[3][0]);
      cst = ff*cst + ii*gg;
      hl = oo*fast_tanh(cst);
      ((_Float16*)hA[cur^1])[eoff] = (_Float16)hl;
    }
  }

  // fused head: out[r] = sum_n h_last[r][n]*wlin[n] + blin
  if (lane < 32) head[rb*128 + en] = hl * wl;
  __syncthreads();
  if (tid < 2) {
    float s = blin[0];
    for (int n = 0; n < 128; ++n) s += head[tid*128 + n];
    out[r0 + tid] = s;
  }
}

extern "C" void kernel_launch(void* const* d_in, const int* in_sizes, int n_in,
                              void* d_out, int out_size, void* d_ws, size_t ws_size,
                              hipStream_t stream)
{
  const float* x    = (const float*)d_in[0];
  const float* wih0 = (const float*)d_in[1];
  const float* whh0 = (const float*)d_in[2];
  const float* bih0 = (const float*)d_in[3];
  const float* bhh0 = (const float*)d_in[4];
  const float* wih1 = (const float*)d_in[5];
  const float* whh1 = (const float*)d_in[6];
  const float* bih1 = (const float*)d_in[7];
  const float* bhh1 = (const float*)d_in[8];
  const float* wlin = (const float*)d_in[9];
  const float* blin = (const float*)d_in[10];
  float* out = (float*)d_out;

  char* ws = (char*)d_ws;
  _Float16* w0f = (_Float16*)(ws);               // 196608 B
  _Float16* w1f = (_Float16*)(ws + 196608);      // 262144 B
  float* bias0  = (float*)(ws + 458752);         // 2048 B
  float* bias1  = (float*)(ws + 460800);         // 2048 B
  _Float16* h1  = (_Float16*)(ws + 1048576);     // 64 MB inter-layer buffer

  prep_kernel<<<256, 256, 0, stream>>>(wih0, whh0, bih0, bhh0, wih1, whh1, bih1, bhh1,
                                       w0f, w1f, bias0, bias1);
  lstm_l0<<<256, 512, 0, stream>>>(x, w0f, bias0, h1);
  lstm_l1<<<256, 512, 0, stream>>>(h1, w1f, bias1, wlin, blin, out);
}